// Round 7
// baseline (229.676 us; speedup 1.0000x reference)
//
#include <hip/hip_runtime.h>

#define CL7_NATOMS 8192
#define CL7_NSHIFT 14
#define CL7_NROWS (CL7_NSHIFT * CL7_NATOMS)  // 114688 rows = (k, i)
#define CL7_NCHUNK 128                       // 8192/64 j-chunks per row
#define CL7_TI 8                             // i-rows per wave in count
#define CL7_NGRP (CL7_NROWS / CL7_TI)        // 14336 groups
#define CL7_NTILE 112                        // scan tiles of 1024 rows
#define CL7_C2 ((float)(5.2 * 5.2))          // f32 compare (JAX weak promotion)

__device__ const int cl7_shifts[CL7_NSHIFT][3] = {
    {0, 0, 0},
    {-1, 0, 0}, {-1, -1, 0}, {0, -1, 0}, {1, -1, 0},
    {-1, 1, -1}, {0, 1, -1}, {1, 1, -1}, {-1, 0, -1},
    {0, 0, -1}, {1, 0, -1}, {-1, -1, -1}, {0, -1, -1}, {1, -1, -1}};

// Module-owned scratch (d_ws unused). Everything read is rewritten each call.
__device__ float4 cl7_pp[CL7_NATOMS];                                    // wrapped coords
__device__ unsigned long long cl7_mask[(size_t)CL7_NROWS * CL7_NCHUNK];  // hit bitmasks
__device__ unsigned cl7_cnt[CL7_NROWS];
__device__ unsigned cl7_off[CL7_NROWS];
__device__ unsigned cl7_tot[CL7_NTILE];
__device__ float4 cl7_dg;             // cell diagonal (f32, from f64 sqrt)
__device__ float4 cl7_sf[CL7_NSHIFT]; // per-shift (sx*dgx, sy*dgy, sz*dgz)

// --- setup: all f64 constant math once -------------------------------------
__global__ void cl7_setup(const float* __restrict__ cell) {
  if (threadIdx.x != 0 || blockIdx.x != 0) return;
  float dgx = (float)sqrt((double)cell[0] * cell[0] + (double)cell[3] * cell[3] +
                          (double)cell[6] * cell[6]);
  float dgy = (float)sqrt((double)cell[1] * cell[1] + (double)cell[4] * cell[4] +
                          (double)cell[7] * cell[7]);
  float dgz = (float)sqrt((double)cell[2] * cell[2] + (double)cell[5] * cell[5] +
                          (double)cell[8] * cell[8]);
  cl7_dg = make_float4(dgx, dgy, dgz, 0.f);
  for (int k = 0; k < CL7_NSHIFT; ++k) {
    cl7_sf[k] = make_float4(__fmul_rn((float)cl7_shifts[k][0], dgx),
                            __fmul_rn((float)cl7_shifts[k][1], dgy),
                            __fmul_rn((float)cl7_shifts[k][2], dgz), 0.f);
  }
}

// --- wrap: frac = x @ inv(cell); frac -= floor; w = frac @ cell (f32 RN) ----
__global__ __launch_bounds__(256) void cl7_wrap(const float* __restrict__ coords,
                                                const float* __restrict__ cell) {
  int i = blockIdx.x * blockDim.x + threadIdx.x;
  if (i >= CL7_NATOMS) return;
  double a00 = cell[0], a01 = cell[1], a02 = cell[2];
  double a10 = cell[3], a11 = cell[4], a12 = cell[5];
  double a20 = cell[6], a21 = cell[7], a22 = cell[8];
  double det = a00 * (a11 * a22 - a12 * a21) - a01 * (a10 * a22 - a12 * a20) +
               a02 * (a10 * a21 - a11 * a20);
  double id = 1.0 / det;
  float inv[3][3];
  inv[0][0] = (float)((a11 * a22 - a12 * a21) * id);
  inv[0][1] = (float)(-(a01 * a22 - a02 * a21) * id);
  inv[0][2] = (float)((a01 * a12 - a02 * a11) * id);
  inv[1][0] = (float)(-(a10 * a22 - a12 * a20) * id);
  inv[1][1] = (float)((a00 * a22 - a02 * a20) * id);
  inv[1][2] = (float)(-(a00 * a12 - a02 * a10) * id);
  inv[2][0] = (float)((a10 * a21 - a11 * a20) * id);
  inv[2][1] = (float)(-(a00 * a21 - a01 * a20) * id);
  inv[2][2] = (float)((a00 * a11 - a01 * a10) * id);

  float x = coords[3 * i], y = coords[3 * i + 1], z = coords[3 * i + 2];
  float fr[3], w[3];
#pragma unroll
  for (int c = 0; c < 3; ++c) {
    float f = __fadd_rn(__fadd_rn(__fmul_rn(x, inv[0][c]), __fmul_rn(y, inv[1][c])),
                        __fmul_rn(z, inv[2][c]));
    fr[c] = __fsub_rn(f, floorf(f));
  }
#pragma unroll
  for (int c = 0; c < 3; ++c) {
    w[c] = __fadd_rn(
        __fadd_rn(__fmul_rn(fr[0], cell[0 * 3 + c]), __fmul_rn(fr[1], cell[1 * 3 + c])),
        __fmul_rn(fr[2], cell[2 * 3 + c]));
  }
  cl7_pp[i] = make_float4(w[0], w[1], w[2], 0.0f);
}

// Slab prune: d2<=c2 forces shifted atom i into a cutoff-wide boundary slab
// (0.09 margin over f32 rounding slack). Pruned rows contribute zero pairs.
__device__ __forceinline__ bool cl7_alive(float xi, float yi, float zi, int sx, int sy,
                                          int sz, float dgx, float dgy, float dgz) {
  bool a = true;
  if (sx < 0) a = a && (xi >= dgx - 5.3f); else if (sx > 0) a = a && (xi <= 5.3f);
  if (sy < 0) a = a && (yi >= dgy - 5.3f); else if (sy > 0) a = a && (yi <= 5.3f);
  if (sz < 0) a = a && (zi >= dgz - 5.3f); else if (sz > 0) a = a && (zi <= 5.3f);
  return a;
}

// --- count: one wave per 8-row group; shared pj load feeds 8 rows ----------
__global__ __launch_bounds__(512) void cl7_count() {
  int grp = blockIdx.x * 8 + (threadIdx.x >> 6);
  int lane = threadIdx.x & 63;
  int k = grp >> 10;               // 1024 groups per shift
  int i0 = (grp & 1023) << 3;

  float4 dg = cl7_dg;
  float4 sc = cl7_sf[k];
  int sx = cl7_shifts[k][0], sy = cl7_shifts[k][1], sz = cl7_shifts[k][2];

  float4 pi[CL7_TI];
  bool alive[CL7_TI];
  bool any = false;
#pragma unroll
  for (int r = 0; r < CL7_TI; ++r) {
    pi[r] = cl7_pp[i0 + r];
    // slab test is wave-uniform; route through ballot so it lands in an SGPR
    bool t = (k == 0) || cl7_alive(pi[r].x, pi[r].y, pi[r].z, sx, sy, sz,
                                   dg.x, dg.y, dg.z);
    alive[r] = (__ballot(t) != 0ull);
    any = any || alive[r];
  }
  int row0 = (k << 13) + i0;
  if (!any) {
    if (lane < CL7_TI) cl7_cnt[row0 + lane] = 0u;
    return;
  }

  unsigned cnt[CL7_TI] = {};
  int jc0 = (k == 0) ? (i0 >> 6) : 0;
  size_t mb = (size_t)row0 * CL7_NCHUNK;
  for (int jc = jc0; jc < CL7_NCHUNK; ++jc) {
    int j = (jc << 6) + lane;
    float4 pj = cl7_pp[j];
#pragma unroll
    for (int r = 0; r < CL7_TI; ++r) {
      if (!alive[r]) continue;  // scalar branch (alive is SGPR-resident)
      float dx = __fadd_rn(__fsub_rn(pi[r].x, pj.x), sc.x);
      float dy = __fadd_rn(__fsub_rn(pi[r].y, pj.y), sc.y);
      float dz = __fadd_rn(__fsub_rn(pi[r].z, pj.z), sc.z);
      float d2 = __fadd_rn(__fadd_rn(__fmul_rn(dx, dx), __fmul_rn(dy, dy)),
                           __fmul_rn(dz, dz));
      bool ok = (d2 <= CL7_C2);
      if (k == 0) ok = ok && ((i0 + r) < j);
      unsigned long long m = __ballot(ok);
      cnt[r] += (unsigned)__popcll(m);
      if (lane == 0) cl7_mask[mb + (size_t)r * CL7_NCHUNK + jc] = m;
    }
  }
  if (lane == 0) {
#pragma unroll
    for (int r = 0; r < CL7_TI; ++r) cl7_cnt[row0 + r] = cnt[r];
  }
}

// --- scan stage 1: per-1024-row tile exclusive scan + tile total ------------
__global__ __launch_bounds__(1024) void cl7_s1() {
  __shared__ unsigned sd[1024];
  int t = threadIdx.x;
  int gid = blockIdx.x * 1024 + t;
  unsigned v = cl7_cnt[gid];
  sd[t] = v;
  __syncthreads();
  unsigned acc = v;
  for (int off = 1; off < 1024; off <<= 1) {
    unsigned a = (t >= off) ? sd[t - off] : 0u;
    __syncthreads();
    acc += a;
    sd[t] = acc;
    __syncthreads();
  }
  cl7_off[gid] = acc - v;
  if (t == 1023) cl7_tot[blockIdx.x] = acc;
}

// --- scan stage 2+3 fused: add sum of preceding tile totals ----------------
__global__ __launch_bounds__(1024) void cl7_s2() {
  __shared__ unsigned sred[16];
  int t = threadIdx.x;
  unsigned v = (t < blockIdx.x) ? cl7_tot[t] : 0u;  // blockIdx.x <= 111 < 1024
#pragma unroll
  for (int off = 32; off; off >>= 1) v += __shfl_down(v, off);
  if ((t & 63) == 0) sred[t >> 6] = v;
  __syncthreads();
  if (t == 0) {
    unsigned b = 0;
#pragma unroll
    for (int w = 0; w < 16; ++w) b += sred[w];
    sred[0] = b;
  }
  __syncthreads();
  cl7_off[blockIdx.x * 1024 + t] += sred[0];
}

__device__ __forceinline__ unsigned cl7_iscan(unsigned v, int lane) {
  for (int off = 1; off < 64; off <<= 1) {
    unsigned t = __shfl_up(v, off);
    if (lane >= off) v += t;
  }
  return v;
}

// --- emit: expand stored masks into [ i xP | j xP | (sx,sy,sz) xP ] ---------
__global__ __launch_bounds__(512) void cl7_emit(int* __restrict__ out, int P) {
  int w = blockIdx.x * 8 + (threadIdx.x >> 6);
  int lane = threadIdx.x & 63;
  int k = w >> 13, i = w & (CL7_NATOMS - 1);

  float4 dg = cl7_dg;
  int sx = cl7_shifts[k][0], sy = cl7_shifts[k][1], sz = cl7_shifts[k][2];

  float4 pi = cl7_pp[i];
  if (k != 0 && !cl7_alive(pi.x, pi.y, pi.z, sx, sy, sz, dg.x, dg.y, dg.z)) return;

  unsigned base = cl7_off[w];
  int jc0 = (k == 0) ? (i >> 6) : 0;
  size_t mb = (size_t)w * CL7_NCHUNK;
  unsigned long long m0 = (lane >= jc0) ? cl7_mask[mb + lane] : 0ull;
  unsigned long long m1 = (64 + lane >= jc0) ? cl7_mask[mb + 64 + lane] : 0ull;
  unsigned c0 = (unsigned)__popcll(m0), c1 = (unsigned)__popcll(m1);

  unsigned s0 = cl7_iscan(c0, lane);
  unsigned T0 = __shfl(s0, 63);
  unsigned e0 = s0 - c0;
  unsigned s1 = cl7_iscan(c1, lane);
  unsigned e1 = T0 + s1 - c1;

  unsigned p = base + e0;
  unsigned long long m = m0;
  while (m) {
    int b = __ffsll((long long)m) - 1;
    m &= m - 1;
    if (p < (unsigned)P) {
      int j = (lane << 6) + b;
      out[p] = i;
      out[P + p] = j;
      unsigned sp = 2u * (unsigned)P + 3u * p;
      out[sp] = sx;
      out[sp + 1] = sy;
      out[sp + 2] = sz;
    }
    ++p;
  }
  p = base + e1;
  m = m1;
  while (m) {
    int b = __ffsll((long long)m) - 1;
    m &= m - 1;
    if (p < (unsigned)P) {
      int j = ((64 + lane) << 6) + b;
      out[p] = i;
      out[P + p] = j;
      unsigned sp = 2u * (unsigned)P + 3u * p;
      out[sp] = sx;
      out[sp + 1] = sy;
      out[sp + 2] = sz;
    }
    ++p;
  }
}

extern "C" void kernel_launch(void* const* d_in, const int* in_sizes, int n_in,
                              void* d_out, int out_size, void* d_ws, size_t ws_size,
                              hipStream_t stream) {
  const float* coords = (const float*)d_in[1];  // (1, N, 3) f32
  const float* cell = (const float*)d_in[2];    // (3, 3) f32
  int P = out_size / 5;

  cl7_setup<<<1, 64, 0, stream>>>(cell);
  cl7_wrap<<<CL7_NATOMS / 256, 256, 0, stream>>>(coords, cell);
  cl7_count<<<CL7_NGRP / 8, 512, 0, stream>>>();
  cl7_s1<<<CL7_NTILE, 1024, 0, stream>>>();
  cl7_s2<<<CL7_NTILE, 1024, 0, stream>>>();
  cl7_emit<<<CL7_NROWS / 8, 512, 0, stream>>>((int*)d_out, P);
}

// Round 9
// 62.550 us; speedup vs baseline: 3.6719x; 3.6719x over previous
//
#include <hip/hip_runtime.h>

#define CL9_NATOMS 8192
#define CL9_NSHIFT 14
#define CL9_NROWS (CL9_NSHIFT * CL9_NATOMS)  // 114688 rows = (k, i)
#define CL9_NTILE 112                        // scan tiles of 1024 rows
#define CL9_NCELL 512                        // 8x8x8 spatial bins
#define CL9_C2 ((float)(5.2 * 5.2))          // f32 compare (JAX weak promotion)
#define CL9_R 5.35f                          // candidate interval half-width

__device__ const int cl9_shifts[CL9_NSHIFT][3] = {
    {0, 0, 0},
    {-1, 0, 0}, {-1, -1, 0}, {0, -1, 0}, {1, -1, 0},
    {-1, 1, -1}, {0, 1, -1}, {1, 1, -1}, {-1, 0, -1},
    {0, 0, -1}, {1, 0, -1}, {-1, -1, -1}, {0, -1, -1}, {1, -1, -1}};

// Module-owned scratch (d_ws unused). Everything read is rewritten each call.
__device__ float4 cl9_pp[CL9_NATOMS];        // wrapped coords
__device__ float4 cl9_sorted[CL9_NATOMS];    // bin-sorted coords, .w = original i
__device__ unsigned cl9_hist[CL9_NCELL];
__device__ unsigned cl9_cstart[CL9_NCELL + 1];
__device__ unsigned cl9_cfill[CL9_NCELL];
__device__ uint4 cl9_mask4[(size_t)CL9_NROWS * 64];  // per-row 128xu64 hit masks
__device__ unsigned cl9_cnt[CL9_NROWS];
__device__ unsigned cl9_off[CL9_NROWS];
__device__ unsigned cl9_tot[CL9_NTILE];
__device__ float4 cl9_dg;              // cell diagonal
__device__ float4 cl9_cinv;            // 8/diag per axis
__device__ float4 cl9_sf[CL9_NSHIFT];  // s * diag (f32, __fmul_rn)

// --- setup: f64 constant math once + zero the bin histogram ----------------
__global__ __launch_bounds__(512) void cl9_setup(const float* __restrict__ cell) {
  int t = threadIdx.x;
  if (t < CL9_NCELL) cl9_hist[t] = 0u;
  if (t == 0) {
    float dgx = (float)sqrt((double)cell[0] * cell[0] + (double)cell[3] * cell[3] +
                            (double)cell[6] * cell[6]);
    float dgy = (float)sqrt((double)cell[1] * cell[1] + (double)cell[4] * cell[4] +
                            (double)cell[7] * cell[7]);
    float dgz = (float)sqrt((double)cell[2] * cell[2] + (double)cell[5] * cell[5] +
                            (double)cell[8] * cell[8]);
    cl9_dg = make_float4(dgx, dgy, dgz, 0.f);
    cl9_cinv = make_float4(8.0f / dgx, 8.0f / dgy, 8.0f / dgz, 0.f);
    for (int k = 0; k < CL9_NSHIFT; ++k)
      cl9_sf[k] = make_float4(__fmul_rn((float)cl9_shifts[k][0], dgx),
                              __fmul_rn((float)cl9_shifts[k][1], dgy),
                              __fmul_rn((float)cl9_shifts[k][2], dgz), 0.f);
  }
}

// --- wrap: frac = x @ inv(cell); frac -= floor; w = frac @ cell (f32 RN) ----
__global__ __launch_bounds__(256) void cl9_wrap(const float* __restrict__ coords,
                                                const float* __restrict__ cell) {
  int i = blockIdx.x * blockDim.x + threadIdx.x;
  if (i >= CL9_NATOMS) return;
  double a00 = cell[0], a01 = cell[1], a02 = cell[2];
  double a10 = cell[3], a11 = cell[4], a12 = cell[5];
  double a20 = cell[6], a21 = cell[7], a22 = cell[8];
  double det = a00 * (a11 * a22 - a12 * a21) - a01 * (a10 * a22 - a12 * a20) +
               a02 * (a10 * a21 - a11 * a20);
  double id = 1.0 / det;
  float inv[3][3];
  inv[0][0] = (float)((a11 * a22 - a12 * a21) * id);
  inv[0][1] = (float)(-(a01 * a22 - a02 * a21) * id);
  inv[0][2] = (float)((a01 * a12 - a02 * a11) * id);
  inv[1][0] = (float)(-(a10 * a22 - a12 * a20) * id);
  inv[1][1] = (float)((a00 * a22 - a02 * a20) * id);
  inv[1][2] = (float)(-(a00 * a12 - a02 * a10) * id);
  inv[2][0] = (float)((a10 * a21 - a11 * a20) * id);
  inv[2][1] = (float)(-(a00 * a21 - a01 * a20) * id);
  inv[2][2] = (float)((a00 * a11 - a01 * a10) * id);

  float x = coords[3 * i], y = coords[3 * i + 1], z = coords[3 * i + 2];
  float fr[3], w[3];
#pragma unroll
  for (int c = 0; c < 3; ++c) {
    float f = __fadd_rn(__fadd_rn(__fmul_rn(x, inv[0][c]), __fmul_rn(y, inv[1][c])),
                        __fmul_rn(z, inv[2][c]));
    fr[c] = __fsub_rn(f, floorf(f));
  }
#pragma unroll
  for (int c = 0; c < 3; ++c) {
    w[c] = __fadd_rn(
        __fadd_rn(__fmul_rn(fr[0], cell[0 * 3 + c]), __fmul_rn(fr[1], cell[1 * 3 + c])),
        __fmul_rn(fr[2], cell[2 * 3 + c]));
  }
  cl9_pp[i] = make_float4(w[0], w[1], w[2], 0.0f);
}

__device__ __forceinline__ int cl9_cellof(const float4& p, const float4& cinv) {
  int cx = min(7, (int)(p.x * cinv.x));
  int cy = min(7, (int)(p.y * cinv.y));
  int cz = min(7, (int)(p.z * cinv.z));
  return (cz * 8 + cy) * 8 + cx;  // x fastest -> contiguous x-runs
}

// --- bin: histogram atoms into 512 cells ------------------------------------
__global__ __launch_bounds__(256) void cl9_bin() {
  int i = blockIdx.x * blockDim.x + threadIdx.x;
  if (i >= CL9_NATOMS) return;
  atomicAdd(&cl9_hist[cl9_cellof(cl9_pp[i], cl9_cinv)], 1u);
}

// --- cscan: exclusive scan of 512 cell counts -------------------------------
__global__ __launch_bounds__(512) void cl9_cscan() {
  __shared__ unsigned sd[512];
  int t = threadIdx.x;
  unsigned v = cl9_hist[t];
  sd[t] = v;
  __syncthreads();
  unsigned acc = v;
  for (int off = 1; off < 512; off <<= 1) {
    unsigned a = (t >= off) ? sd[t - off] : 0u;
    __syncthreads();
    acc += a;
    sd[t] = acc;
    __syncthreads();
  }
  cl9_cstart[t] = acc - v;
  cl9_cfill[t] = acc - v;
  if (t == 511) cl9_cstart[512] = acc;
}

// --- scatter: bin-sort atoms (intra-cell order nondeterministic; output-
// invariant since hits are recorded as bits keyed by original index) ---------
__global__ __launch_bounds__(256) void cl9_scatter() {
  int i = blockIdx.x * blockDim.x + threadIdx.x;
  if (i >= CL9_NATOMS) return;
  float4 p = cl9_pp[i];
  int c = cl9_cellof(p, cl9_cinv);
  unsigned pos = atomicAdd(&cl9_cfill[c], 1u);
  p.w = __int_as_float(i);
  cl9_sorted[pos] = p;
}

// Slab prune: d2<=c2 forces shifted atom i into a cutoff-wide boundary slab
// (0.09 margin over f32 rounding slack). Pruned rows contribute zero pairs.
__device__ __forceinline__ bool cl9_alive(float xi, float yi, float zi, int sx, int sy,
                                          int sz, float dgx, float dgy, float dgz) {
  bool a = true;
  if (sx < 0) a = a && (xi >= dgx - 5.3f); else if (sx > 0) a = a && (xi <= 5.3f);
  if (sy < 0) a = a && (yi >= dgy - 5.3f); else if (sy > 0) a = a && (yi <= 5.3f);
  if (sz < 0) a = a && (zi >= dgz - 5.3f); else if (sz > 0) a = a && (zi <= 5.3f);
  return a;
}

// Candidate cell range on one axis for target coordinate t (monotone-rounding
// safe: RN multiply preserves order; 0.14 slack vs exact test >> f32 ulp).
__device__ __forceinline__ void cl9_crange(float t, float ci, int& lo, int& hi) {
  lo = max(0, (int)(fmaxf(t - CL9_R, 0.f) * ci));
  hi = min(7, (int)(fmaxf(t + CL9_R, 0.f) * ci));
}

// --- count: one wave per (k,i) row; test only cell-list candidates, set bits
// in an LDS mask, write the full 1KB mask coalesced + row count --------------
__global__ __launch_bounds__(512) void cl9_count() {
  __shared__ uint4 smask[8][64];  // 1KB mask per wave
  int wv = blockIdx.x * 8 + (threadIdx.x >> 6);
  int lane = threadIdx.x & 63;
  unsigned* lm = (unsigned*)smask[threadIdx.x >> 6];
  int k = wv >> 13, i = wv & (CL9_NATOMS - 1);

  float4 dg = cl9_dg;
  float4 sc = cl9_sf[k];
  int sx = cl9_shifts[k][0], sy = cl9_shifts[k][1], sz = cl9_shifts[k][2];
  float4 pi = cl9_pp[i];
  if (k != 0 && !cl9_alive(pi.x, pi.y, pi.z, sx, sy, sz, dg.x, dg.y, dg.z)) {
    if (lane == 0) cl9_cnt[wv] = 0u;
    return;
  }
  smask[threadIdx.x >> 6][lane] = make_uint4(0u, 0u, 0u, 0u);

  float4 cinv = cl9_cinv;
  int xlo, xhi, ylo, yhi, zlo, zhi;
  cl9_crange(__fadd_rn(pi.x, sc.x), cinv.x, xlo, xhi);
  cl9_crange(__fadd_rn(pi.y, sc.y), cinv.y, ylo, yhi);
  cl9_crange(__fadd_rn(pi.z, sc.z), cinv.z, zlo, zhi);

  for (int cz = zlo; cz <= zhi; ++cz) {
    for (int cy = ylo; cy <= yhi; ++cy) {
      int idb = (cz * 8 + cy) * 8;
      unsigned b = cl9_cstart[idb + xlo], e = cl9_cstart[idb + xhi + 1];
      for (unsigned t = b + lane; t < e; t += 64) {
        float4 pj = cl9_sorted[t];
        int j = __float_as_int(pj.w);
        float dx = __fadd_rn(__fsub_rn(pi.x, pj.x), sc.x);
        float dy = __fadd_rn(__fsub_rn(pi.y, pj.y), sc.y);
        float dz = __fadd_rn(__fsub_rn(pi.z, pj.z), sc.z);
        float d2 = __fadd_rn(__fadd_rn(__fmul_rn(dx, dx), __fmul_rn(dy, dy)),
                             __fmul_rn(dz, dz));
        bool ok = (d2 <= CL9_C2) && (k != 0 || i < j);
        if (ok) atomicOr(&lm[(unsigned)j >> 5], 1u << (j & 31));
      }
    }
  }
  uint4 v = smask[threadIdx.x >> 6][lane];
  cl9_mask4[(size_t)wv * 64 + lane] = v;
  unsigned s = __popc(v.x) + __popc(v.y) + __popc(v.z) + __popc(v.w);
#pragma unroll
  for (int off = 32; off; off >>= 1) s += __shfl_down(s, off);
  if (lane == 0) cl9_cnt[wv] = s;
}

// --- scan stage 1: per-1024-row tile exclusive scan + tile total ------------
__global__ __launch_bounds__(1024) void cl9_s1() {
  __shared__ unsigned sd[1024];
  int t = threadIdx.x;
  int gid = blockIdx.x * 1024 + t;
  unsigned v = cl9_cnt[gid];
  sd[t] = v;
  __syncthreads();
  unsigned acc = v;
  for (int off = 1; off < 1024; off <<= 1) {
    unsigned a = (t >= off) ? sd[t - off] : 0u;
    __syncthreads();
    acc += a;
    sd[t] = acc;
    __syncthreads();
  }
  cl9_off[gid] = acc - v;
  if (t == 1023) cl9_tot[blockIdx.x] = acc;
}

// --- scan stage 2+3 fused: add sum of preceding tile totals ----------------
__global__ __launch_bounds__(1024) void cl9_s2() {
  __shared__ unsigned sred[16];
  int t = threadIdx.x;
  unsigned v = (t < blockIdx.x) ? cl9_tot[t] : 0u;  // blockIdx.x <= 111 < 1024
#pragma unroll
  for (int off = 32; off; off >>= 1) v += __shfl_down(v, off);
  if ((t & 63) == 0) sred[t >> 6] = v;
  __syncthreads();
  if (t == 0) {
    unsigned b = 0;
#pragma unroll
    for (int w = 0; w < 16; ++w) b += sred[w];
    sred[0] = b;
  }
  __syncthreads();
  cl9_off[blockIdx.x * 1024 + t] += sred[0];
}

__device__ __forceinline__ unsigned cl9_iscan(unsigned v, int lane) {
  for (int off = 1; off < 64; off <<= 1) {
    unsigned t = __shfl_up(v, off);
    if (lane >= off) v += t;
  }
  return v;
}

// --- emit: expand full masks into [ i xP | j xP | (sx,sy,sz) xP ] -----------
__global__ __launch_bounds__(512) void cl9_emit(int* __restrict__ out, int P) {
  int wv = blockIdx.x * 8 + (threadIdx.x >> 6);
  int lane = threadIdx.x & 63;
  int k = wv >> 13, i = wv & (CL9_NATOMS - 1);

  float4 dg = cl9_dg;
  int sx = cl9_shifts[k][0], sy = cl9_shifts[k][1], sz = cl9_shifts[k][2];
  float4 pi = cl9_pp[i];
  if (k != 0 && !cl9_alive(pi.x, pi.y, pi.z, sx, sy, sz, dg.x, dg.y, dg.z)) return;

  unsigned base = cl9_off[wv];
  const unsigned long long* mrow =
      (const unsigned long long*)(cl9_mask4 + (size_t)wv * 64);
  unsigned long long m0 = mrow[lane];       // j in [64*lane, 64*lane+64)
  unsigned long long m1 = mrow[64 + lane];  // j in [4096 + 64*lane, ...)
  unsigned c0 = (unsigned)__popcll(m0), c1 = (unsigned)__popcll(m1);

  unsigned s0 = cl9_iscan(c0, lane);
  unsigned T0 = __shfl(s0, 63);
  unsigned e0 = s0 - c0;
  unsigned s1 = cl9_iscan(c1, lane);
  unsigned e1 = T0 + s1 - c1;

  unsigned p = base + e0;
  unsigned long long m = m0;
  while (m) {
    int b = __ffsll((long long)m) - 1;
    m &= m - 1;
    if (p < (unsigned)P) {
      int j = (lane << 6) + b;
      out[p] = i;
      out[P + p] = j;
      unsigned sp = 2u * (unsigned)P + 3u * p;
      out[sp] = sx;
      out[sp + 1] = sy;
      out[sp + 2] = sz;
    }
    ++p;
  }
  p = base + e1;
  m = m1;
  while (m) {
    int b = __ffsll((long long)m) - 1;
    m &= m - 1;
    if (p < (unsigned)P) {
      int j = ((64 + lane) << 6) + b;
      out[p] = i;
      out[P + p] = j;
      unsigned sp = 2u * (unsigned)P + 3u * p;
      out[sp] = sx;
      out[sp + 1] = sy;
      out[sp + 2] = sz;
    }
    ++p;
  }
}

extern "C" void kernel_launch(void* const* d_in, const int* in_sizes, int n_in,
                              void* d_out, int out_size, void* d_ws, size_t ws_size,
                              hipStream_t stream) {
  const float* coords = (const float*)d_in[1];  // (1, N, 3) f32
  const float* cell = (const float*)d_in[2];    // (3, 3) f32
  int P = out_size / 5;

  cl9_setup<<<1, 512, 0, stream>>>(cell);
  cl9_wrap<<<CL9_NATOMS / 256, 256, 0, stream>>>(coords, cell);
  cl9_bin<<<CL9_NATOMS / 256, 256, 0, stream>>>();
  cl9_cscan<<<1, 512, 0, stream>>>();
  cl9_scatter<<<CL9_NATOMS / 256, 256, 0, stream>>>();
  cl9_count<<<CL9_NROWS / 8, 512, 0, stream>>>();   // one wave per row
  cl9_s1<<<CL9_NTILE, 1024, 0, stream>>>();
  cl9_s2<<<CL9_NTILE, 1024, 0, stream>>>();
  cl9_emit<<<CL9_NROWS / 8, 512, 0, stream>>>((int*)d_out, P);  // one wave per row
}